// Round 1
// baseline (511.391 us; speedup 1.0000x reference)
//
#include <hip/hip_runtime.h>
#include <hip/hip_bf16.h>
#include <cmath>

#define HDIM 2048
#define NEXP 16
#define IDIM 512
#define ISDIM 2048
#define NTOK 2048
#define MAXTILES 80
#define ROWSCAP (MAXTILES * 64)

typedef short bf16x8 __attribute__((ext_vector_type(8)));
typedef float f32x4 __attribute__((ext_vector_type(4)));

__device__ __forceinline__ unsigned short f2bf(float f) {
  unsigned int u = __builtin_bit_cast(unsigned int, f);
  u += 0x7FFFu + ((u >> 16) & 1u);
  return (unsigned short)(u >> 16);
}

// stage 8 consecutive fp32 -> 8 bf16 into LDS (16B write)
__device__ __forceinline__ void stage_w8(const float* __restrict__ src,
                                         unsigned short* __restrict__ dst) {
  const float4* p = reinterpret_cast<const float4*>(src);
  float4 a = p[0];
  float4 b = p[1];
  bf16x8 v = {(short)f2bf(a.x), (short)f2bf(a.y), (short)f2bf(a.z), (short)f2bf(a.w),
              (short)f2bf(b.x), (short)f2bf(b.y), (short)f2bf(b.z), (short)f2bf(b.w)};
  *reinterpret_cast<bf16x8*>(dst) = v;
}

// ---------------- kernel 1: fp32 x -> bf16 xb, zero counts ----------------
__global__ __launch_bounds__(256) void k_prep(const float* __restrict__ x,
                                              unsigned short* __restrict__ xb,
                                              int* __restrict__ counts) {
  int i = blockIdx.x * 256 + threadIdx.x;  // one float4 per thread
  float4 v = reinterpret_cast<const float4*>(x)[i];
  ushort4 o;
  o.x = f2bf(v.x); o.y = f2bf(v.y); o.z = f2bf(v.z); o.w = f2bf(v.w);
  reinterpret_cast<ushort4*>(xb)[i] = o;
  if (blockIdx.x == 0 && threadIdx.x < NEXP) counts[threadIdx.x] = 0;
}

// ---------------- kernel 2: router (fp32 exact) + shared sigmoid gate -----
__global__ __launch_bounds__(256) void k_router(const float* __restrict__ x,
                                                const float* __restrict__ gate_w,
                                                const float* __restrict__ sgw,
                                                int* __restrict__ sel,
                                                float* __restrict__ wnorm,
                                                float* __restrict__ sig,
                                                int* __restrict__ counts) {
  __shared__ float xs[HDIM];
  __shared__ float logits[NEXP];
  __shared__ float red[4];
  int t = blockIdx.x;
  int tid = threadIdx.x;
  for (int i = tid; i < HDIM / 4; i += 256) {
    float4 v = reinterpret_cast<const float4*>(x + (size_t)t * HDIM)[i];
    xs[i * 4 + 0] = v.x; xs[i * 4 + 1] = v.y; xs[i * 4 + 2] = v.z; xs[i * 4 + 3] = v.w;
  }
  __syncthreads();
  // 16 threads per expert
  int e = tid >> 4, j = tid & 15;
  float p = 0.f;
  const float* gw = gate_w + (size_t)e * HDIM;
  for (int i = j; i < HDIM; i += 16) p += xs[i] * gw[i];
  for (int off = 8; off; off >>= 1) p += __shfl_xor(p, off, 16);
  if (j == 0) logits[e] = p;
  // shared gate dot, all 256 threads
  float q = 0.f;
  for (int i = tid; i < HDIM; i += 256) q += xs[i] * sgw[i];
  for (int off = 32; off; off >>= 1) q += __shfl_xor(q, off, 64);
  int wid = tid >> 6;
  if ((tid & 63) == 0) red[wid] = q;
  __syncthreads();
  if (tid == 0) {
    float sq = red[0] + red[1] + red[2] + red[3];
    sig[t] = 1.f / (1.f + expf(-sq));
    float m = logits[0];
    for (int i = 1; i < NEXP; i++) m = fmaxf(m, logits[i]);
    float pe[NEXP];
    for (int i = 0; i < NEXP; i++) pe[i] = expf(logits[i] - m);
    // top-2 (first index wins ties, matching lax.top_k)
    int i1 = 0; float v1 = pe[0];
    for (int i = 1; i < NEXP; i++) if (pe[i] > v1) { v1 = pe[i]; i1 = i; }
    int i2 = (i1 == 0) ? 1 : 0; float v2 = pe[i2];
    for (int i = 0; i < NEXP; i++)
      if (i != i1 && i != i2 && pe[i] > v2) { v2 = pe[i]; i2 = i; }
    float tw = v1 + v2;  // softmax denominator cancels in renorm
    sel[t * 2] = i1; sel[t * 2 + 1] = i2;
    wnorm[t * 2] = v1 / tw; wnorm[t * 2 + 1] = v2 / tw;
    atomicAdd(&counts[i1], 1);
    atomicAdd(&counts[i2], 1);
  }
}

// ---------------- kernel 3: scan -> aligned offsets, tile map -------------
__global__ __launch_bounds__(256) void k_scan(const int* __restrict__ counts,
                                              int* __restrict__ offs,
                                              int* __restrict__ tile_expert,
                                              int* __restrict__ row_token,
                                              int* __restrict__ fillpos) {
  int tid = threadIdx.x;
  if (tid == 0) {
    int acc = 0;
    for (int e = 0; e < NEXP; e++) {
      offs[e] = acc;
      int nt = (counts[e] + 63) >> 6;
      for (int i = 0; i < nt; i++) tile_expert[(acc >> 6) + i] = e;
      acc += nt << 6;
    }
    for (int m = acc >> 6; m < MAXTILES; m++) tile_expert[m] = -1;
  }
  for (int r = tid; r < ROWSCAP; r += 256) row_token[r] = -1;
  if (tid < NEXP) fillpos[tid] = 0;
}

// ---------------- kernel 4: scatter tokens into compact rows --------------
__global__ __launch_bounds__(256) void k_scatter(const int* __restrict__ sel,
                                                 const int* __restrict__ offs,
                                                 int* __restrict__ fillpos,
                                                 int* __restrict__ row_token,
                                                 int* __restrict__ tok2row) {
  int t = blockIdx.x * 256 + threadIdx.x;
  for (int k = 0; k < 2; k++) {
    int e = sel[t * 2 + k];
    int pos = atomicAdd(&fillpos[e], 1);
    int row = offs[e] + pos;
    row_token[row] = t;
    tok2row[t * 2 + k] = row;
  }
}

// ---------------- kernel 5: expert gate/up fused (gathered A) -------------
__global__ __launch_bounds__(256) void k_expert_gu(
    const unsigned short* __restrict__ xb, const float* __restrict__ w1,
    const float* __restrict__ w3, const int* __restrict__ tile_expert,
    const int* __restrict__ row_token, unsigned short* __restrict__ hmid) {
  int mt = blockIdx.y, nt = blockIdx.x;
  int e = tile_expert[mt];
  if (e < 0) return;
  __shared__ unsigned short As[64 * 72];
  __shared__ unsigned short Bg[64 * 72];
  __shared__ unsigned short Bu[64 * 72];
  __shared__ int toks[64];
  int tid = threadIdx.x;
  if (tid < 64) {
    int tk = row_token[mt * 64 + tid];
    toks[tid] = tk < 0 ? 0 : tk;
  }
  const float* w1e = w1 + ((size_t)e * IDIM + nt * 64) * HDIM;
  const float* w3e = w3 + ((size_t)e * IDIM + nt * 64) * HDIM;
  int wave = tid >> 6, lane = tid & 63;
  int wm = wave >> 1, wn = wave & 1;
  int quad = lane >> 4, l16 = lane & 15;
  int r0 = tid >> 3, kof0 = (tid & 7) << 3;
  int c2 = tid + 256;
  int r1 = c2 >> 3, kof1 = (c2 & 7) << 3;
  f32x4 accG[2][2] = {};
  f32x4 accU[2][2] = {};
  __syncthreads();
  for (int k0 = 0; k0 < HDIM; k0 += 64) {
    *reinterpret_cast<bf16x8*>(&As[r0 * 72 + kof0]) =
        *reinterpret_cast<const bf16x8*>(xb + (size_t)toks[r0] * HDIM + k0 + kof0);
    *reinterpret_cast<bf16x8*>(&As[r1 * 72 + kof1]) =
        *reinterpret_cast<const bf16x8*>(xb + (size_t)toks[r1] * HDIM + k0 + kof1);
    stage_w8(w1e + (size_t)r0 * HDIM + k0 + kof0, &Bg[r0 * 72 + kof0]);
    stage_w8(w1e + (size_t)r1 * HDIM + k0 + kof1, &Bg[r1 * 72 + kof1]);
    stage_w8(w3e + (size_t)r0 * HDIM + k0 + kof0, &Bu[r0 * 72 + kof0]);
    stage_w8(w3e + (size_t)r1 * HDIM + k0 + kof1, &Bu[r1 * 72 + kof1]);
    __syncthreads();
#pragma unroll
    for (int ks = 0; ks < 2; ks++) {
      bf16x8 af[2], bg[2], bu[2];
#pragma unroll
      for (int ms = 0; ms < 2; ms++)
        af[ms] = *reinterpret_cast<const bf16x8*>(
            &As[(wm * 32 + ms * 16 + l16) * 72 + ks * 32 + quad * 8]);
#pragma unroll
      for (int ns = 0; ns < 2; ns++) {
        bg[ns] = *reinterpret_cast<const bf16x8*>(
            &Bg[(wn * 32 + ns * 16 + l16) * 72 + ks * 32 + quad * 8]);
        bu[ns] = *reinterpret_cast<const bf16x8*>(
            &Bu[(wn * 32 + ns * 16 + l16) * 72 + ks * 32 + quad * 8]);
      }
#pragma unroll
      for (int ms = 0; ms < 2; ms++)
#pragma unroll
        for (int ns = 0; ns < 2; ns++) {
          accG[ms][ns] = __builtin_amdgcn_mfma_f32_16x16x32_bf16(af[ms], bg[ns], accG[ms][ns], 0, 0, 0);
          accU[ms][ns] = __builtin_amdgcn_mfma_f32_16x16x32_bf16(af[ms], bu[ns], accU[ms][ns], 0, 0, 0);
        }
    }
    __syncthreads();
  }
#pragma unroll
  for (int ms = 0; ms < 2; ms++)
#pragma unroll
    for (int ns = 0; ns < 2; ns++)
#pragma unroll
      for (int r = 0; r < 4; r++) {
        float g = accG[ms][ns][r], u = accU[ms][ns][r];
        float hv = (g / (1.f + __expf(-g))) * u;
        int row = mt * 64 + wm * 32 + ms * 16 + quad * 4 + r;
        int col = nt * 64 + wn * 32 + ns * 16 + l16;
        hmid[(size_t)row * IDIM + col] = f2bf(hv);
      }
}

// ---------------- kernel 6: expert down -> moe_rows (fp32) ----------------
__global__ __launch_bounds__(256) void k_expert_down(
    const unsigned short* __restrict__ hmid, const float* __restrict__ w2,
    const int* __restrict__ tile_expert, float* __restrict__ moe_rows) {
  int mt = blockIdx.y, nt = blockIdx.x;
  int e = tile_expert[mt];
  if (e < 0) return;
  __shared__ unsigned short As[64 * 72];
  __shared__ unsigned short Bs[64 * 72];
  int tid = threadIdx.x;
  const float* w2e = w2 + ((size_t)e * HDIM + nt * 64) * IDIM;
  int wave = tid >> 6, lane = tid & 63;
  int wm = wave >> 1, wn = wave & 1;
  int quad = lane >> 4, l16 = lane & 15;
  int r0 = tid >> 3, kof0 = (tid & 7) << 3;
  int c2 = tid + 256;
  int r1 = c2 >> 3, kof1 = (c2 & 7) << 3;
  f32x4 acc[2][2] = {};
  for (int k0 = 0; k0 < IDIM; k0 += 64) {
    *reinterpret_cast<bf16x8*>(&As[r0 * 72 + kof0]) =
        *reinterpret_cast<const bf16x8*>(hmid + (size_t)(mt * 64 + r0) * IDIM + k0 + kof0);
    *reinterpret_cast<bf16x8*>(&As[r1 * 72 + kof1]) =
        *reinterpret_cast<const bf16x8*>(hmid + (size_t)(mt * 64 + r1) * IDIM + k0 + kof1);
    stage_w8(w2e + (size_t)r0 * IDIM + k0 + kof0, &Bs[r0 * 72 + kof0]);
    stage_w8(w2e + (size_t)r1 * IDIM + k0 + kof1, &Bs[r1 * 72 + kof1]);
    __syncthreads();
#pragma unroll
    for (int ks = 0; ks < 2; ks++) {
      bf16x8 af[2], bf[2];
#pragma unroll
      for (int ms = 0; ms < 2; ms++)
        af[ms] = *reinterpret_cast<const bf16x8*>(
            &As[(wm * 32 + ms * 16 + l16) * 72 + ks * 32 + quad * 8]);
#pragma unroll
      for (int ns = 0; ns < 2; ns++)
        bf[ns] = *reinterpret_cast<const bf16x8*>(
            &Bs[(wn * 32 + ns * 16 + l16) * 72 + ks * 32 + quad * 8]);
#pragma unroll
      for (int ms = 0; ms < 2; ms++)
#pragma unroll
        for (int ns = 0; ns < 2; ns++)
          acc[ms][ns] = __builtin_amdgcn_mfma_f32_16x16x32_bf16(af[ms], bf[ns], acc[ms][ns], 0, 0, 0);
    }
    __syncthreads();
  }
#pragma unroll
  for (int ms = 0; ms < 2; ms++)
#pragma unroll
    for (int ns = 0; ns < 2; ns++)
#pragma unroll
      for (int r = 0; r < 4; r++) {
        int row = mt * 64 + wm * 32 + ms * 16 + quad * 4 + r;
        int col = nt * 64 + wn * 32 + ns * 16 + l16;
        moe_rows[(size_t)row * HDIM + col] = acc[ms][ns][r];
      }
}

// ---------------- kernel 7: shared gate/up fused --------------------------
__global__ __launch_bounds__(256) void k_shared_gu(
    const unsigned short* __restrict__ xb, const float* __restrict__ wg,
    const float* __restrict__ wu, unsigned short* __restrict__ hs) {
  int mt = blockIdx.y, nt = blockIdx.x;
  __shared__ unsigned short As[64 * 72];
  __shared__ unsigned short Bg[64 * 72];
  __shared__ unsigned short Bu[64 * 72];
  int tid = threadIdx.x;
  const float* wge = wg + (size_t)(nt * 64) * HDIM;
  const float* wue = wu + (size_t)(nt * 64) * HDIM;
  int wave = tid >> 6, lane = tid & 63;
  int wm = wave >> 1, wn = wave & 1;
  int quad = lane >> 4, l16 = lane & 15;
  int r0 = tid >> 3, kof0 = (tid & 7) << 3;
  int c2 = tid + 256;
  int r1 = c2 >> 3, kof1 = (c2 & 7) << 3;
  f32x4 accG[2][2] = {};
  f32x4 accU[2][2] = {};
  for (int k0 = 0; k0 < HDIM; k0 += 64) {
    *reinterpret_cast<bf16x8*>(&As[r0 * 72 + kof0]) =
        *reinterpret_cast<const bf16x8*>(xb + (size_t)(mt * 64 + r0) * HDIM + k0 + kof0);
    *reinterpret_cast<bf16x8*>(&As[r1 * 72 + kof1]) =
        *reinterpret_cast<const bf16x8*>(xb + (size_t)(mt * 64 + r1) * HDIM + k0 + kof1);
    stage_w8(wge + (size_t)r0 * HDIM + k0 + kof0, &Bg[r0 * 72 + kof0]);
    stage_w8(wge + (size_t)r1 * HDIM + k0 + kof1, &Bg[r1 * 72 + kof1]);
    stage_w8(wue + (size_t)r0 * HDIM + k0 + kof0, &Bu[r0 * 72 + kof0]);
    stage_w8(wue + (size_t)r1 * HDIM + k0 + kof1, &Bu[r1 * 72 + kof1]);
    __syncthreads();
#pragma unroll
    for (int ks = 0; ks < 2; ks++) {
      bf16x8 af[2], bg[2], bu[2];
#pragma unroll
      for (int ms = 0; ms < 2; ms++)
        af[ms] = *reinterpret_cast<const bf16x8*>(
            &As[(wm * 32 + ms * 16 + l16) * 72 + ks * 32 + quad * 8]);
#pragma unroll
      for (int ns = 0; ns < 2; ns++) {
        bg[ns] = *reinterpret_cast<const bf16x8*>(
            &Bg[(wn * 32 + ns * 16 + l16) * 72 + ks * 32 + quad * 8]);
        bu[ns] = *reinterpret_cast<const bf16x8*>(
            &Bu[(wn * 32 + ns * 16 + l16) * 72 + ks * 32 + quad * 8]);
      }
#pragma unroll
      for (int ms = 0; ms < 2; ms++)
#pragma unroll
        for (int ns = 0; ns < 2; ns++) {
          accG[ms][ns] = __builtin_amdgcn_mfma_f32_16x16x32_bf16(af[ms], bg[ns], accG[ms][ns], 0, 0, 0);
          accU[ms][ns] = __builtin_amdgcn_mfma_f32_16x16x32_bf16(af[ms], bu[ns], accU[ms][ns], 0, 0, 0);
        }
    }
    __syncthreads();
  }
#pragma unroll
  for (int ms = 0; ms < 2; ms++)
#pragma unroll
    for (int ns = 0; ns < 2; ns++)
#pragma unroll
      for (int r = 0; r < 4; r++) {
        float g = accG[ms][ns][r], u = accU[ms][ns][r];
        float hv = (g / (1.f + __expf(-g))) * u;
        int row = mt * 64 + wm * 32 + ms * 16 + quad * 4 + r;
        int col = nt * 64 + wn * 32 + ns * 16 + l16;
        hs[(size_t)row * ISDIM + col] = f2bf(hv);
      }
}

// -------- kernel 8: shared down + final combine (sig*shared + moe) --------
__global__ __launch_bounds__(256) void k_shared_down(
    const unsigned short* __restrict__ hs, const float* __restrict__ wsd,
    const float* __restrict__ moe_rows, const int* __restrict__ tok2row,
    const float* __restrict__ wnorm, const float* __restrict__ sig,
    float* __restrict__ out) {
  int mt = blockIdx.y, nt = blockIdx.x;
  __shared__ unsigned short As[64 * 72];
  __shared__ unsigned short Bs[64 * 72];
  int tid = threadIdx.x;
  const float* wsde = wsd + (size_t)(nt * 64) * ISDIM;
  int wave = tid >> 6, lane = tid & 63;
  int wm = wave >> 1, wn = wave & 1;
  int quad = lane >> 4, l16 = lane & 15;
  int r0 = tid >> 3, kof0 = (tid & 7) << 3;
  int c2 = tid + 256;
  int r1 = c2 >> 3, kof1 = (c2 & 7) << 3;
  f32x4 acc[2][2] = {};
  for (int k0 = 0; k0 < ISDIM; k0 += 64) {
    *reinterpret_cast<bf16x8*>(&As[r0 * 72 + kof0]) =
        *reinterpret_cast<const bf16x8*>(hs + (size_t)(mt * 64 + r0) * ISDIM + k0 + kof0);
    *reinterpret_cast<bf16x8*>(&As[r1 * 72 + kof1]) =
        *reinterpret_cast<const bf16x8*>(hs + (size_t)(mt * 64 + r1) * ISDIM + k0 + kof1);
    stage_w8(wsde + (size_t)r0 * ISDIM + k0 + kof0, &Bs[r0 * 72 + kof0]);
    stage_w8(wsde + (size_t)r1 * ISDIM + k0 + kof1, &Bs[r1 * 72 + kof1]);
    __syncthreads();
#pragma unroll
    for (int ks = 0; ks < 2; ks++) {
      bf16x8 af[2], bf[2];
#pragma unroll
      for (int ms = 0; ms < 2; ms++)
        af[ms] = *reinterpret_cast<const bf16x8*>(
            &As[(wm * 32 + ms * 16 + l16) * 72 + ks * 32 + quad * 8]);
#pragma unroll
      for (int ns = 0; ns < 2; ns++)
        bf[ns] = *reinterpret_cast<const bf16x8*>(
            &Bs[(wn * 32 + ns * 16 + l16) * 72 + ks * 32 + quad * 8]);
#pragma unroll
      for (int ms = 0; ms < 2; ms++)
#pragma unroll
        for (int ns = 0; ns < 2; ns++)
          acc[ms][ns] = __builtin_amdgcn_mfma_f32_16x16x32_bf16(af[ms], bf[ns], acc[ms][ns], 0, 0, 0);
    }
    __syncthreads();
  }
#pragma unroll
  for (int ms = 0; ms < 2; ms++)
#pragma unroll
    for (int ns = 0; ns < 2; ns++)
#pragma unroll
      for (int r = 0; r < 4; r++) {
        int t = mt * 64 + wm * 32 + ms * 16 + quad * 4 + r;
        int col = nt * 64 + wn * 32 + ns * 16 + l16;
        float v = acc[ms][ns][r] * sig[t];
        int ra = tok2row[t * 2], rb = tok2row[t * 2 + 1];
        v += wnorm[t * 2] * moe_rows[(size_t)ra * HDIM + col] +
             wnorm[t * 2 + 1] * moe_rows[(size_t)rb * HDIM + col];
        out[(size_t)t * HDIM + col] = v;
      }
}

extern "C" void kernel_launch(void* const* d_in, const int* in_sizes, int n_in,
                              void* d_out, int out_size, void* d_ws, size_t ws_size,
                              hipStream_t stream) {
  const float* x = (const float*)d_in[0];
  const float* gate_w = (const float*)d_in[1];
  const float* w1 = (const float*)d_in[2];
  const float* w2 = (const float*)d_in[3];
  const float* w3 = (const float*)d_in[4];
  const float* wsg = (const float*)d_in[5];
  const float* wsu = (const float*)d_in[6];
  const float* wsd = (const float*)d_in[7];
  const float* sgw = (const float*)d_in[8];
  float* out = (float*)d_out;

  // workspace carve (all 16B-aligned)
  unsigned short* xb = (unsigned short*)d_ws;              // NTOK*HDIM bf16
  unsigned short* hs = xb + (size_t)NTOK * HDIM;           // NTOK*ISDIM bf16
  unsigned short* hmid = hs + (size_t)NTOK * ISDIM;        // ROWSCAP*IDIM bf16
  float* moe_rows = (float*)(hmid + (size_t)ROWSCAP * IDIM);  // ROWSCAP*HDIM f32
  float* wnorm = moe_rows + (size_t)ROWSCAP * HDIM;        // 2*NTOK f32
  float* sig = wnorm + 2 * NTOK;                           // NTOK f32
  int* sel = (int*)(sig + NTOK);                           // 2*NTOK
  int* tok2row = sel + 2 * NTOK;                           // 2*NTOK
  int* row_token = tok2row + 2 * NTOK;                     // ROWSCAP
  int* counts = row_token + ROWSCAP;                       // NEXP
  int* offs = counts + NEXP;                               // NEXP
  int* fillpos = offs + NEXP;                              // NEXP
  int* tile_expert = fillpos + NEXP;                       // MAXTILES

  k_prep<<<dim3((NTOK * HDIM) / 1024), dim3(256), 0, stream>>>(x, xb, counts);
  k_router<<<dim3(NTOK), dim3(256), 0, stream>>>(x, gate_w, sgw, sel, wnorm, sig, counts);
  k_scan<<<dim3(1), dim3(256), 0, stream>>>(counts, offs, tile_expert, row_token, fillpos);
  k_scatter<<<dim3(NTOK / 256), dim3(256), 0, stream>>>(sel, offs, fillpos, row_token, tok2row);
  k_expert_gu<<<dim3(IDIM / 64, MAXTILES), dim3(256), 0, stream>>>(
      xb, w1, w3, tile_expert, row_token, hmid);
  k_expert_down<<<dim3(HDIM / 64, MAXTILES), dim3(256), 0, stream>>>(
      hmid, w2, tile_expert, moe_rows);
  k_shared_gu<<<dim3(ISDIM / 64, NTOK / 64), dim3(256), 0, stream>>>(xb, wsg, wsu, hs);
  k_shared_down<<<dim3(HDIM / 64, NTOK / 64), dim3(256), 0, stream>>>(
      hs, wsd, moe_rows, tok2row, wnorm, sig, out);
}

// Round 2
// 482.389 us; speedup vs baseline: 1.0601x; 1.0601x over previous
//
#include <hip/hip_runtime.h>
#include <hip/hip_bf16.h>
#include <cmath>

#define HDIM 2048
#define NEXP 16
#define IDIM 512
#define ISDIM 2048
#define NTOK 2048
#define MAXTILES 80
#define ROWSCAP (MAXTILES * 64)
#define NB_EXP 640   // (IDIM/64) * MAXTILES
#define NB_SH 1024   // (ISDIM/64) * (NTOK/64)

typedef short bf16x8 __attribute__((ext_vector_type(8)));
typedef float f32x4 __attribute__((ext_vector_type(4)));

__device__ __forceinline__ unsigned short f2bf(float f) {
  unsigned int u = __builtin_bit_cast(unsigned int, f);
  u += 0x7FFFu + ((u >> 16) & 1u);
  return (unsigned short)(u >> 16);
}

// stage 8 consecutive fp32 -> 8 bf16 into LDS (16B write)
__device__ __forceinline__ void stage_w8(const float* __restrict__ src,
                                         unsigned short* __restrict__ dst) {
  const float4* p = reinterpret_cast<const float4*>(src);
  float4 a = p[0];
  float4 b = p[1];
  bf16x8 v = {(short)f2bf(a.x), (short)f2bf(a.y), (short)f2bf(a.z), (short)f2bf(a.w),
              (short)f2bf(b.x), (short)f2bf(b.y), (short)f2bf(b.z), (short)f2bf(b.w)};
  *reinterpret_cast<bf16x8*>(dst) = v;
}

// ------- kernel 1: router (wave per token) + x->bf16 conversion fused -----
__global__ __launch_bounds__(256) void k_router(const float* __restrict__ x,
                                                const float* __restrict__ gate_w,
                                                const float* __restrict__ sgw,
                                                unsigned short* __restrict__ xb,
                                                int* __restrict__ sel,
                                                float* __restrict__ wnorm,
                                                float* __restrict__ sig,
                                                int* __restrict__ counts) {
  __shared__ float lg[4][17];
  int tid = threadIdx.x, wid = tid >> 6, lane = tid & 63;
  int t = blockIdx.x * 4 + wid;
  const float4* xrow = reinterpret_cast<const float4*>(x + (size_t)t * HDIM);
  float4 xv[8];
#pragma unroll
  for (int s = 0; s < 8; s++) xv[s] = xrow[s * 64 + lane];
  // write bf16 copy of x (replaces old k_prep)
  ushort4* xbrow = reinterpret_cast<ushort4*>(xb + (size_t)t * HDIM);
#pragma unroll
  for (int s = 0; s < 8; s++) {
    ushort4 o;
    o.x = f2bf(xv[s].x); o.y = f2bf(xv[s].y); o.z = f2bf(xv[s].z); o.w = f2bf(xv[s].w);
    xbrow[s * 64 + lane] = o;
  }
  // 17 dots: 16 experts + shared sigmoid gate, coalesced reads
#pragma unroll 1
  for (int e = 0; e < 17; e++) {
    const float4* gr =
        reinterpret_cast<const float4*>(e < 16 ? gate_w + (size_t)e * HDIM : sgw);
    float acc = 0.f;
#pragma unroll
    for (int s = 0; s < 8; s++) {
      float4 g = gr[s * 64 + lane];
      acc += xv[s].x * g.x + xv[s].y * g.y + xv[s].z * g.z + xv[s].w * g.w;
    }
#pragma unroll
    for (int off = 32; off; off >>= 1) acc += __shfl_xor(acc, off, 64);
    if (lane == 0) lg[wid][e] = acc;
  }
  if (lane == 0) {
    float* L = lg[wid];
    int i1 = 0; float v1 = L[0];
    for (int i = 1; i < NEXP; i++) if (L[i] > v1) { v1 = L[i]; i1 = i; }
    int i2 = (i1 == 0) ? 1 : 0; float v2 = L[i2];
    for (int i = 0; i < NEXP; i++)
      if (i != i1 && i != i2 && L[i] > v2) { v2 = L[i]; i2 = i; }
    // renormalized top-2 softmax == softmax over {v1,v2}
    float wa = 1.f / (1.f + expf(v2 - v1));
    sel[2 * t] = i1; sel[2 * t + 1] = i2;
    wnorm[2 * t] = wa; wnorm[2 * t + 1] = 1.f - wa;
    sig[t] = 1.f / (1.f + expf(-L[16]));
    atomicAdd(&counts[i1], 1);
    atomicAdd(&counts[i2], 1);
  }
}

// ------- kernel 2: scan + scatter in a single block -----------------------
__global__ __launch_bounds__(256) void k_scan_scatter(const int* __restrict__ counts,
                                                      const int* __restrict__ sel,
                                                      int* __restrict__ tile_expert,
                                                      int* __restrict__ row_token,
                                                      int* __restrict__ tok2row) {
  __shared__ int offs_s[NEXP];
  __shared__ int fill_s[NEXP];
  int tid = threadIdx.x;
  for (int r = tid; r < ROWSCAP; r += 256) row_token[r] = -1;
  if (tid < NEXP) fill_s[tid] = 0;
  if (tid == 0) {
    int acc = 0;
    for (int e = 0; e < NEXP; e++) {
      offs_s[e] = acc;
      int nt = (counts[e] + 63) >> 6;
      for (int i = 0; i < nt; i++) tile_expert[(acc >> 6) + i] = e;
      acc += nt << 6;
    }
    for (int m = acc >> 6; m < MAXTILES; m++) tile_expert[m] = -1;
  }
  __syncthreads();
  for (int t = tid; t < NTOK; t += 256) {
    for (int k = 0; k < 2; k++) {
      int e = sel[2 * t + k];
      int pos = atomicAdd(&fill_s[e], 1);
      int row = offs_s[e] + pos;
      row_token[row] = t;
      tok2row[2 * t + k] = row;
    }
  }
}

// ------- kernel 3: fused gate/up GEMM for experts AND shared expert -------
__global__ __launch_bounds__(256) void k_gu(
    const unsigned short* __restrict__ xb, const float* __restrict__ w1,
    const float* __restrict__ w3, const float* __restrict__ wsg,
    const float* __restrict__ wsu, const int* __restrict__ tile_expert,
    const int* __restrict__ row_token, unsigned short* __restrict__ hmid,
    unsigned short* __restrict__ hs) {
  __shared__ unsigned short As[64 * 72];
  __shared__ unsigned short Bg[64 * 72];
  __shared__ unsigned short Bu[64 * 72];
  __shared__ int toks[64];
  int bid = blockIdx.x, tid = threadIdx.x;
  const float *bGp, *bUp;
  unsigned short* outp;
  int ostride, mt, ncol;
  if (bid < NB_EXP) {
    mt = bid >> 3;
    int nt = bid & 7;
    int e = tile_expert[mt];
    if (e < 0) return;
    if (tid < 64) {
      int tk = row_token[mt * 64 + tid];
      toks[tid] = tk < 0 ? 0 : tk;
    }
    bGp = w1 + ((size_t)e * IDIM + nt * 64) * HDIM;
    bUp = w3 + ((size_t)e * IDIM + nt * 64) * HDIM;
    outp = hmid; ostride = IDIM; ncol = nt * 64;
  } else {
    int sb = bid - NB_EXP;
    mt = sb >> 5;
    int nt = sb & 31;
    if (tid < 64) toks[tid] = mt * 64 + tid;
    bGp = wsg + (size_t)(nt * 64) * HDIM;
    bUp = wsu + (size_t)(nt * 64) * HDIM;
    outp = hs; ostride = ISDIM; ncol = nt * 64;
  }
  int wave = tid >> 6, lane = tid & 63;
  int wm = wave >> 1, wn = wave & 1;
  int quad = lane >> 4, l16 = lane & 15;
  int r0 = tid >> 3, kof0 = (tid & 7) << 3;
  int c2 = tid + 256;
  int r1 = c2 >> 3, kof1 = (c2 & 7) << 3;
  f32x4 accG[2][2] = {};
  f32x4 accU[2][2] = {};
  __syncthreads();
  for (int k0 = 0; k0 < HDIM; k0 += 64) {
    *reinterpret_cast<bf16x8*>(&As[r0 * 72 + kof0]) =
        *reinterpret_cast<const bf16x8*>(xb + (size_t)toks[r0] * HDIM + k0 + kof0);
    *reinterpret_cast<bf16x8*>(&As[r1 * 72 + kof1]) =
        *reinterpret_cast<const bf16x8*>(xb + (size_t)toks[r1] * HDIM + k0 + kof1);
    stage_w8(bGp + (size_t)r0 * HDIM + k0 + kof0, &Bg[r0 * 72 + kof0]);
    stage_w8(bGp + (size_t)r1 * HDIM + k0 + kof1, &Bg[r1 * 72 + kof1]);
    stage_w8(bUp + (size_t)r0 * HDIM + k0 + kof0, &Bu[r0 * 72 + kof0]);
    stage_w8(bUp + (size_t)r1 * HDIM + k0 + kof1, &Bu[r1 * 72 + kof1]);
    __syncthreads();
#pragma unroll
    for (int ks = 0; ks < 2; ks++) {
      bf16x8 af[2], bg[2], bu[2];
#pragma unroll
      for (int ms = 0; ms < 2; ms++)
        af[ms] = *reinterpret_cast<const bf16x8*>(
            &As[(wm * 32 + ms * 16 + l16) * 72 + ks * 32 + quad * 8]);
#pragma unroll
      for (int ns = 0; ns < 2; ns++) {
        bg[ns] = *reinterpret_cast<const bf16x8*>(
            &Bg[(wn * 32 + ns * 16 + l16) * 72 + ks * 32 + quad * 8]);
        bu[ns] = *reinterpret_cast<const bf16x8*>(
            &Bu[(wn * 32 + ns * 16 + l16) * 72 + ks * 32 + quad * 8]);
      }
#pragma unroll
      for (int ms = 0; ms < 2; ms++)
#pragma unroll
        for (int ns = 0; ns < 2; ns++) {
          accG[ms][ns] = __builtin_amdgcn_mfma_f32_16x16x32_bf16(af[ms], bg[ns], accG[ms][ns], 0, 0, 0);
          accU[ms][ns] = __builtin_amdgcn_mfma_f32_16x16x32_bf16(af[ms], bu[ns], accU[ms][ns], 0, 0, 0);
        }
    }
    __syncthreads();
  }
#pragma unroll
  for (int ms = 0; ms < 2; ms++)
#pragma unroll
    for (int ns = 0; ns < 2; ns++)
#pragma unroll
      for (int r = 0; r < 4; r++) {
        float g = accG[ms][ns][r], u = accU[ms][ns][r];
        float hv = (g / (1.f + __expf(-g))) * u;
        int row = mt * 64 + wm * 32 + ms * 16 + quad * 4 + r;
        int col = ncol + wn * 32 + ns * 16 + l16;
        outp[(size_t)row * ostride + col] = f2bf(hv);
      }
}

// ---------------- kernel 4: expert down -> moe_rows (fp32) ----------------
__global__ __launch_bounds__(256) void k_expert_down(
    const unsigned short* __restrict__ hmid, const float* __restrict__ w2,
    const int* __restrict__ tile_expert, float* __restrict__ moe_rows) {
  int mt = blockIdx.y, nt = blockIdx.x;
  int e = tile_expert[mt];
  if (e < 0) return;
  __shared__ unsigned short As[64 * 72];
  __shared__ unsigned short Bs[64 * 72];
  int tid = threadIdx.x;
  const float* w2e = w2 + ((size_t)e * HDIM + nt * 64) * IDIM;
  int wave = tid >> 6, lane = tid & 63;
  int wm = wave >> 1, wn = wave & 1;
  int quad = lane >> 4, l16 = lane & 15;
  int r0 = tid >> 3, kof0 = (tid & 7) << 3;
  int c2 = tid + 256;
  int r1 = c2 >> 3, kof1 = (c2 & 7) << 3;
  f32x4 acc[2][2] = {};
  for (int k0 = 0; k0 < IDIM; k0 += 64) {
    *reinterpret_cast<bf16x8*>(&As[r0 * 72 + kof0]) =
        *reinterpret_cast<const bf16x8*>(hmid + (size_t)(mt * 64 + r0) * IDIM + k0 + kof0);
    *reinterpret_cast<bf16x8*>(&As[r1 * 72 + kof1]) =
        *reinterpret_cast<const bf16x8*>(hmid + (size_t)(mt * 64 + r1) * IDIM + k0 + kof1);
    stage_w8(w2e + (size_t)r0 * IDIM + k0 + kof0, &Bs[r0 * 72 + kof0]);
    stage_w8(w2e + (size_t)r1 * IDIM + k0 + kof1, &Bs[r1 * 72 + kof1]);
    __syncthreads();
#pragma unroll
    for (int ks = 0; ks < 2; ks++) {
      bf16x8 af[2], bf[2];
#pragma unroll
      for (int ms = 0; ms < 2; ms++)
        af[ms] = *reinterpret_cast<const bf16x8*>(
            &As[(wm * 32 + ms * 16 + l16) * 72 + ks * 32 + quad * 8]);
#pragma unroll
      for (int ns = 0; ns < 2; ns++)
        bf[ns] = *reinterpret_cast<const bf16x8*>(
            &Bs[(wn * 32 + ns * 16 + l16) * 72 + ks * 32 + quad * 8]);
#pragma unroll
      for (int ms = 0; ms < 2; ms++)
#pragma unroll
        for (int ns = 0; ns < 2; ns++)
          acc[ms][ns] = __builtin_amdgcn_mfma_f32_16x16x32_bf16(af[ms], bf[ns], acc[ms][ns], 0, 0, 0);
    }
    __syncthreads();
  }
#pragma unroll
  for (int ms = 0; ms < 2; ms++)
#pragma unroll
    for (int ns = 0; ns < 2; ns++)
#pragma unroll
      for (int r = 0; r < 4; r++) {
        int row = mt * 64 + wm * 32 + ms * 16 + quad * 4 + r;
        int col = nt * 64 + wn * 32 + ns * 16 + l16;
        moe_rows[(size_t)row * HDIM + col] = acc[ms][ns][r];
      }
}

// -------- kernel 5: shared down + final combine (sig*shared + moe) --------
__global__ __launch_bounds__(256) void k_shared_down(
    const unsigned short* __restrict__ hs, const float* __restrict__ wsd,
    const float* __restrict__ moe_rows, const int* __restrict__ tok2row,
    const float* __restrict__ wnorm, const float* __restrict__ sig,
    float* __restrict__ out) {
  int mt = blockIdx.y, nt = blockIdx.x;
  __shared__ unsigned short As[64 * 72];
  __shared__ unsigned short Bs[64 * 72];
  int tid = threadIdx.x;
  const float* wsde = wsd + (size_t)(nt * 64) * ISDIM;
  int wave = tid >> 6, lane = tid & 63;
  int wm = wave >> 1, wn = wave & 1;
  int quad = lane >> 4, l16 = lane & 15;
  int r0 = tid >> 3, kof0 = (tid & 7) << 3;
  int c2 = tid + 256;
  int r1 = c2 >> 3, kof1 = (c2 & 7) << 3;
  f32x4 acc[2][2] = {};
  for (int k0 = 0; k0 < ISDIM; k0 += 64) {
    *reinterpret_cast<bf16x8*>(&As[r0 * 72 + kof0]) =
        *reinterpret_cast<const bf16x8*>(hs + (size_t)(mt * 64 + r0) * ISDIM + k0 + kof0);
    *reinterpret_cast<bf16x8*>(&As[r1 * 72 + kof1]) =
        *reinterpret_cast<const bf16x8*>(hs + (size_t)(mt * 64 + r1) * ISDIM + k0 + kof1);
    stage_w8(wsde + (size_t)r0 * ISDIM + k0 + kof0, &Bs[r0 * 72 + kof0]);
    stage_w8(wsde + (size_t)r1 * ISDIM + k0 + kof1, &Bs[r1 * 72 + kof1]);
    __syncthreads();
#pragma unroll
    for (int ks = 0; ks < 2; ks++) {
      bf16x8 af[2], bf[2];
#pragma unroll
      for (int ms = 0; ms < 2; ms++)
        af[ms] = *reinterpret_cast<const bf16x8*>(
            &As[(wm * 32 + ms * 16 + l16) * 72 + ks * 32 + quad * 8]);
#pragma unroll
      for (int ns = 0; ns < 2; ns++)
        bf[ns] = *reinterpret_cast<const bf16x8*>(
            &Bs[(wn * 32 + ns * 16 + l16) * 72 + ks * 32 + quad * 8]);
#pragma unroll
      for (int ms = 0; ms < 2; ms++)
#pragma unroll
        for (int ns = 0; ns < 2; ns++)
          acc[ms][ns] = __builtin_amdgcn_mfma_f32_16x16x32_bf16(af[ms], bf[ns], acc[ms][ns], 0, 0, 0);
    }
    __syncthreads();
  }
#pragma unroll
  for (int ms = 0; ms < 2; ms++)
#pragma unroll
    for (int ns = 0; ns < 2; ns++)
#pragma unroll
      for (int r = 0; r < 4; r++) {
        int t = mt * 64 + wm * 32 + ms * 16 + quad * 4 + r;
        int col = nt * 64 + wn * 32 + ns * 16 + l16;
        float v = acc[ms][ns][r] * sig[t];
        int ra = tok2row[t * 2], rb = tok2row[t * 2 + 1];
        v += wnorm[t * 2] * moe_rows[(size_t)ra * HDIM + col] +
             wnorm[t * 2 + 1] * moe_rows[(size_t)rb * HDIM + col];
        out[(size_t)t * HDIM + col] = v;
      }
}

extern "C" void kernel_launch(void* const* d_in, const int* in_sizes, int n_in,
                              void* d_out, int out_size, void* d_ws, size_t ws_size,
                              hipStream_t stream) {
  const float* x = (const float*)d_in[0];
  const float* gate_w = (const float*)d_in[1];
  const float* w1 = (const float*)d_in[2];
  const float* w2 = (const float*)d_in[3];
  const float* w3 = (const float*)d_in[4];
  const float* wsg = (const float*)d_in[5];
  const float* wsu = (const float*)d_in[6];
  const float* wsd = (const float*)d_in[7];
  const float* sgw = (const float*)d_in[8];
  float* out = (float*)d_out;

  // workspace carve (all 16B-aligned)
  unsigned short* xb = (unsigned short*)d_ws;                 // NTOK*HDIM bf16
  unsigned short* hs = xb + (size_t)NTOK * HDIM;              // NTOK*ISDIM bf16
  unsigned short* hmid = hs + (size_t)NTOK * ISDIM;           // ROWSCAP*IDIM bf16
  float* moe_rows = (float*)(hmid + (size_t)ROWSCAP * IDIM);  // ROWSCAP*HDIM f32
  float* wnorm = moe_rows + (size_t)ROWSCAP * HDIM;           // 2*NTOK f32
  float* sig = wnorm + 2 * NTOK;                              // NTOK f32
  int* sel = (int*)(sig + NTOK);                              // 2*NTOK
  int* tok2row = sel + 2 * NTOK;                              // 2*NTOK
  int* row_token = tok2row + 2 * NTOK;                        // ROWSCAP
  int* counts = row_token + ROWSCAP;                          // NEXP
  int* tile_expert = counts + NEXP;                           // MAXTILES

  hipMemsetAsync(counts, 0, NEXP * sizeof(int), stream);
  k_router<<<dim3(NTOK / 4), dim3(256), 0, stream>>>(x, gate_w, sgw, xb, sel, wnorm,
                                                     sig, counts);
  k_scan_scatter<<<dim3(1), dim3(256), 0, stream>>>(counts, sel, tile_expert,
                                                    row_token, tok2row);
  k_gu<<<dim3(NB_EXP + NB_SH), dim3(256), 0, stream>>>(xb, w1, w3, wsg, wsu,
                                                       tile_expert, row_token, hmid, hs);
  k_expert_down<<<dim3(HDIM / 64, MAXTILES), dim3(256), 0, stream>>>(
      hmid, w2, tile_expert, moe_rows);
  k_shared_down<<<dim3(HDIM / 64, NTOK / 64), dim3(256), 0, stream>>>(
      hs, wsd, moe_rows, tok2row, wnorm, sig, out);
}